// Round 10
// baseline (223.395 us; speedup 1.0000x reference)
//
#include <hip/hip_runtime.h>
#include <hip/hip_bf16.h>
#include <stdint.h>

#define B_SZ 2
#define S_LEN 2048
#define D_MODEL 2048
#define NH 32
#define NG 8
#define HGRP 4
#define DHEAD 64
#define KV_DIM 512       // NG*DHEAD
#define M_TOK 4096       // B_SZ*S_LEN
#define KVB 64           // attention KV tile
#define QBLK 256

typedef __attribute__((ext_vector_type(8))) short bf16x8;
typedef __attribute__((ext_vector_type(4))) float f32x4;
typedef __attribute__((ext_vector_type(16))) float f32x16;

__device__ inline unsigned short f2bf(float x) {
    uint32_t u = __builtin_bit_cast(uint32_t, x);
    uint32_t r = (u + 0x7fffu + ((u >> 16) & 1u)) >> 16;
    return (unsigned short)r;
}

__device__ inline uint32_t cvtpk(float lo, float hi) {
    uint32_t r;
    asm("v_cvt_pk_bf16_f32 %0, %1, %2" : "=v"(r) : "v"(lo), "v"(hi));
    return r;
}

__device__ inline void plswap(uint32_t& a, uint32_t& b) {
    asm volatile("v_permlane32_swap_b32 %0, %1" : "+v"(a), "+v"(b));
}

__device__ inline float bf2f(unsigned short u) {
    uint32_t x = ((uint32_t)u) << 16;
    return __builtin_bit_cast(float, x);
}

__device__ inline void async_copy16(const void* g, void* l) {
    __builtin_amdgcn_global_load_lds(
        (const __attribute__((address_space(1))) void*)g,
        (__attribute__((address_space(3))) void*)l,
        16, 0, 0);
}

__device__ inline void gbar() {
    asm volatile("" ::: "memory");
    __builtin_amdgcn_s_barrier();
    asm volatile("" ::: "memory");
}
__device__ inline void lgkm0() {
    asm volatile("s_waitcnt lgkmcnt(0)" ::: "memory");
    __builtin_amdgcn_sched_barrier(0);
}

__device__ inline float vmax16(const f32x16& v) {
    float a0 = fmaxf(v[0], v[1]), a1 = fmaxf(v[2], v[3]);
    float a2 = fmaxf(v[4], v[5]), a3 = fmaxf(v[6], v[7]);
    float a4 = fmaxf(v[8], v[9]), a5 = fmaxf(v[10], v[11]);
    float a6 = fmaxf(v[12], v[13]), a7 = fmaxf(v[14], v[15]);
    float b0 = fmaxf(a0, a1), b1 = fmaxf(a2, a3);
    float b2 = fmaxf(a4, a5), b3 = fmaxf(a6, a7);
    return fmaxf(fmaxf(b0, b1), fmaxf(b2, b3));
}
__device__ inline float vsum16(const f32x16& v) {
    float a0 = v[0] + v[1], a1 = v[2] + v[3], a2 = v[4] + v[5], a3 = v[6] + v[7];
    float a4 = v[8] + v[9], a5 = v[10] + v[11], a6 = v[12] + v[13], a7 = v[14] + v[15];
    float b0 = a0 + a1, b1 = a2 + a3, b2 = a4 + a5, b3 = a6 + a7;
    return (b0 + b1) + (b2 + b3);
}

// ---------------- f32 -> bf16 convert, WEIGHTS ONLY ----------------
__global__ __launch_bounds__(256) void cvt_w(const float* __restrict__ wq,
                                             const float* __restrict__ wk,
                                             const float* __restrict__ wv,
                                             const float* __restrict__ wo,
                                             unsigned short* __restrict__ wqb,
                                             unsigned short* __restrict__ wkvb,
                                             unsigned short* __restrict__ wob) {
    const int i = blockIdx.x * 256 + threadIdx.x;
    const float* src; unsigned short* dst; int j;
    if (i < 524288)      { src = wq; dst = wqb; j = i; }
    else if (i < 655360) { src = wk; dst = wkvb; j = i - 524288; }
    else if (i < 786432) { src = wv; dst = wkvb + (size_t)KV_DIM * D_MODEL; j = i - 655360; }
    else                 { src = wo; dst = wob; j = i - 786432; }
    const float4* p = reinterpret_cast<const float4*>(src) + (size_t)j * 2;
    float4 a = p[0], b = p[1];
    union { unsigned short u[8]; uint4 v4; } r;
    r.u[0] = f2bf(a.x); r.u[1] = f2bf(a.y); r.u[2] = f2bf(a.z); r.u[3] = f2bf(a.w);
    r.u[4] = f2bf(b.x); r.u[5] = f2bf(b.y); r.u[6] = f2bf(b.z); r.u[7] = f2bf(b.w);
    reinterpret_cast<uint4*>(dst)[j] = r.v4;
}

#define SCALE_Q 0.1803368867f   // 0.125 * log2(e)
#define GK 2048

// ---------------- proj GEMM: 256x256 8-phase, f32 A with fused conversion ----
// A (q/k/v) read as f32 and converted in reg-staging (issue early / write late);
// B (weights) bf16 via global_load_lds. N-stacked q|k|v as before.
__global__ __launch_bounds__(512, 2) void gemm8p(const float* __restrict__ Aqf,
                                                 const float* __restrict__ Akf,
                                                 const float* __restrict__ Avf,
                                                 const unsigned short* __restrict__ Bq,
                                                 const unsigned short* __restrict__ Bkv,
                                                 unsigned short* __restrict__ out_q,
                                                 unsigned short* __restrict__ out_k,
                                                 unsigned short* __restrict__ out_v) {
    __shared__ __align__(16) char lds[131072];

    const int tid = threadIdx.x;
    const int lane = tid & 63;
    const int w = tid >> 6;
    const int wm = w >> 2, wn = w & 3;
    const int l15 = lane & 15, l4 = lane >> 4;

    int bid = blockIdx.x;
    bid = (bid & 7) * 24 + (bid >> 3);      // bijective XCD swizzle, 192 blocks
    const int mb = bid & 15, nb = bid >> 4;
    const int m0 = mb * 256;

    const float* Af;
    const unsigned short* Bp;
    int mode = 0, n0q = 0;
    if (nb < 8) {
        Af = Aqf; Bp = Bq + (size_t)(nb * 256) * GK; mode = 0; n0q = nb * 256;
    } else if (nb < 10) {
        Af = Akf; Bp = Bkv + (size_t)((nb - 8) * 256) * GK; mode = 1; n0q = (nb - 8) * 256;
    } else {
        Af = Avf; Bp = Bkv + (size_t)((nb - 10) * 256 + 512) * GK; mode = 2; n0q = (nb - 10) * 256;
    }

    const int srow = tid >> 3;
    const int gcol = (((tid & 7) * 16) ^ ((srow & 7) << 4)) >> 1;   // element index
    char* const myl = lds + tid * 16;

    // A: issue 8 dwordx4 f32 loads early; convert+ds_write late (T14 split).
    float4 av[8];
    auto issueA = [&](int tile) {
#pragma unroll
        for (int h = 0; h < 2; ++h)
#pragma unroll
            for (int r2 = 0; r2 < 2; ++r2) {
                const float* s = Af + (size_t)(m0 + h * 128 + srow + r2 * 64) * GK + tile * 64 + gcol;
                av[(h * 2 + r2) * 2 + 0] = *reinterpret_cast<const float4*>(s);
                av[(h * 2 + r2) * 2 + 1] = *reinterpret_cast<const float4*>(s + 4);
            }
    };
    auto writeA = [&](int tile) {
#pragma unroll
        for (int h = 0; h < 2; ++h)
#pragma unroll
            for (int r2 = 0; r2 < 2; ++r2) {
                const float4 x = av[(h * 2 + r2) * 2 + 0];
                const float4 y = av[(h * 2 + r2) * 2 + 1];
                uint4 o;
                o.x = cvtpk(x.x, x.y); o.y = cvtpk(x.z, x.w);
                o.z = cvtpk(y.x, y.y); o.w = cvtpk(y.z, y.w);
                *reinterpret_cast<uint4*>(myl + (tile & 1) * 32768 + h * 16384 + r2 * 8192) = o;
            }
    };
    auto stageB = [&](int tile, int half) {
        char* dst = myl + 65536 + (tile & 1) * 32768 + half * 16384;
        const unsigned short* src = Bp + (size_t)(half * 128 + srow) * GK + tile * 64 + gcol;
        async_copy16(src, dst);
        async_copy16(src + (size_t)64 * GK, dst + 8192);
    };

    bf16x8 af[4][2], bf[4][2];
    auto loadA = [&](int buf, int mhalf) {
        const char* base = lds + buf * 32768;
#pragma unroll
        for (int mi = 0; mi < 4; ++mi) {
            const int r = wm * 128 + mhalf * 64 + mi * 16 + l15;
#pragma unroll
            for (int ks = 0; ks < 2; ++ks)
                af[mi][ks] = *reinterpret_cast<const bf16x8*>(
                    base + r * 128 + ((ks * 64 + l4 * 16) ^ ((r & 7) << 4)));
        }
    };
    auto loadB = [&](int buf, int nhalf) {
        const char* base = lds + 65536 + buf * 32768;
#pragma unroll
        for (int ni2 = 0; ni2 < 2; ++ni2) {
            const int ni = nhalf * 2 + ni2;
            const int r = wn * 64 + ni * 16 + l15;
#pragma unroll
            for (int ks = 0; ks < 2; ++ks)
                bf[ni][ks] = *reinterpret_cast<const bf16x8*>(
                    base + r * 128 + ((ks * 64 + l4 * 16) ^ ((r & 7) << 4)));
        }
    };

    f32x4 acc[8][4] = {};
    auto mfma16 = [&](int mq, int nq) {
        __builtin_amdgcn_s_setprio(1);
#pragma unroll
        for (int mi = 0; mi < 4; ++mi)
#pragma unroll
            for (int ni2 = 0; ni2 < 2; ++ni2)
#pragma unroll
                for (int ks = 0; ks < 2; ++ks)
                    acc[mq * 4 + mi][nq * 2 + ni2] = __builtin_amdgcn_mfma_f32_16x16x32_bf16(
                        af[mi][ks], bf[nq * 2 + ni2][ks], acc[mq * 4 + mi][nq * 2 + ni2], 0, 0, 0);
        __builtin_amdgcn_s_setprio(0);
    };

    // prologue: A(0) f32 issue + B(0),B(1) gload_lds; convert A(0); land B(0)
    issueA(0);
    stageB(0, 0); stageB(0, 1); stageB(1, 0); stageB(1, 1);
    writeA(0);                                   // compiler waits for av loads
    asm volatile("s_waitcnt vmcnt(4) lgkmcnt(0)" ::: "memory");
    gbar();

    for (int i = 0; i < 16; ++i) {
        const int u = 2 * i;
        const bool nl = (i < 15);
        // ---------- tile u (buf 0) ----------
        loadA(0, 0); loadB(0, 0); issueA(u + 1);
        gbar(); lgkm0(); mfma16(0, 0); gbar();
        loadB(0, 1);
        gbar(); lgkm0(); mfma16(0, 1); gbar();
        loadA(0, 1); if (nl) stageB(u + 2, 0);
        gbar(); lgkm0(); mfma16(1, 0); gbar();
        if (nl) stageB(u + 2, 1);
        gbar(); mfma16(1, 1);
        if (nl) asm volatile("s_waitcnt vmcnt(4)" ::: "memory");
        else    asm volatile("s_waitcnt vmcnt(0)" ::: "memory");
        writeA(u + 1);
        asm volatile("s_waitcnt lgkmcnt(0)" ::: "memory");
        gbar();
        // ---------- tile u+1 (buf 1) ----------
        loadA(1, 0); loadB(1, 0); if (nl) issueA(u + 2);
        gbar(); lgkm0(); mfma16(0, 0); gbar();
        loadB(1, 1);
        gbar(); lgkm0(); mfma16(0, 1); gbar();
        loadA(1, 1); if (nl) stageB(u + 3, 0);
        gbar(); lgkm0(); mfma16(1, 0); gbar();
        if (nl) stageB(u + 3, 1);
        gbar(); mfma16(1, 1);
        if (nl) {
            asm volatile("s_waitcnt vmcnt(4)" ::: "memory");
            writeA(u + 2);
        }
        asm volatile("s_waitcnt lgkmcnt(0)" ::: "memory");
        gbar();
    }

    if (mode == 0) {
#pragma unroll
        for (int mi = 0; mi < 8; ++mi) {
            const int row = m0 + wm * 128 + mi * 16 + l4 * 4;
#pragma unroll
            for (int ni = 0; ni < 4; ++ni) {
                const int col = n0q + wn * 64 + ni * 16 + l15;
#pragma unroll
                for (int r = 0; r < 4; ++r)
                    out_q[(size_t)(row + r) * D_MODEL + col] = f2bf(acc[mi][ni][r] * SCALE_Q);
            }
        }
    } else if (mode == 1) {
#pragma unroll
        for (int mi = 0; mi < 8; ++mi) {
            const int row = m0 + wm * 128 + mi * 16 + l4 * 4;
#pragma unroll
            for (int ni = 0; ni < 4; ++ni) {
                const int col = n0q + wn * 64 + ni * 16 + l15;
#pragma unroll
                for (int r = 0; r < 4; ++r)
                    out_k[(size_t)(row + r) * KV_DIM + col] = f2bf(acc[mi][ni][r]);
            }
        }
    } else {
        const int bb = m0 >> 11;
#pragma unroll
        for (int mi = 0; mi < 8; ++mi) {
            const int tok = (m0 & 2047) + wm * 128 + mi * 16 + l4 * 4;
#pragma unroll
            for (int ni = 0; ni < 4; ++ni) {
                const int c = n0q + wn * 64 + ni * 16 + l15;
                const int g = c >> 6, dh = c & 63;
                uint2 pk;
                pk.x = cvtpk(acc[mi][ni][0], acc[mi][ni][1]);
                pk.y = cvtpk(acc[mi][ni][2], acc[mi][ni][3]);
                *reinterpret_cast<uint2*>(out_v + (size_t)((bb * NG + g) * DHEAD + dh) * S_LEN + tok) = pk;
            }
        }
    }
}

// ---------------- out-proj GEMM: 256x128 8-phase, grid 256 = full GPU ----------------
__global__ __launch_bounds__(512, 1) void gemm8o(const unsigned short* __restrict__ A,
                                                 const unsigned short* __restrict__ B,
                                                 float* __restrict__ C) {
    __shared__ __align__(16) char lds[98304];

    const int tid = threadIdx.x;
    const int lane = tid & 63;
    const int w = tid >> 6;
    const int wm = w >> 1, wn = w & 1;
    const int l15 = lane & 15, l4 = lane >> 4;

    int bid = blockIdx.x;
    bid = (bid & 7) * 32 + (bid >> 3);      // bijective XCD swizzle, 256 blocks
    const int mb = bid & 15, nb = bid >> 4;
    const int m0 = mb * 256, n0 = nb * 128;
    const unsigned short* Bp = B + (size_t)n0 * GK;

    const int srow = tid >> 3;
    const int gcol = (((tid & 7) * 16) ^ ((srow & 7) << 4)) >> 1;

    auto stageA = [&](int tile, int half) {
        char* dst = lds + (tile & 1) * 32768 + half * 16384 + tid * 16;
        const unsigned short* src = A + (size_t)(m0 + half * 128 + srow) * GK + tile * 64 + gcol;
        async_copy16(src, dst);
        async_copy16(src + (size_t)64 * GK, dst + 8192);
    };
    auto stageB = [&](int tile, int half) {
        char* dst = lds + 65536 + (tile & 1) * 16384 + half * 8192 + tid * 16;
        const unsigned short* src = Bp + (size_t)(half * 64 + srow) * GK + tile * 64 + gcol;
        async_copy16(src, dst);
    };

    bf16x8 af[2][2], bf[4][2];
    auto loadA2 = [&](int buf, int mhalf) {
        const char* base = lds + buf * 32768;
#pragma unroll
        for (int mi = 0; mi < 2; ++mi) {
            const int r = wm * 64 + mhalf * 32 + mi * 16 + l15;
#pragma unroll
            for (int ks = 0; ks < 2; ++ks)
                af[mi][ks] = *reinterpret_cast<const bf16x8*>(
                    base + r * 128 + ((ks * 64 + l4 * 16) ^ ((r & 7) << 4)));
        }
    };
    auto loadB2 = [&](int buf, int nhalf) {
        const char* base = lds + 65536 + buf * 16384;
#pragma unroll
        for (int ni2 = 0; ni2 < 2; ++ni2) {
            const int ni = nhalf * 2 + ni2;
            const int r = wn * 64 + ni * 16 + l15;
#pragma unroll
            for (int ks = 0; ks < 2; ++ks)
                bf[ni][ks] = *reinterpret_cast<const bf16x8*>(
                    base + r * 128 + ((ks * 64 + l4 * 16) ^ ((r & 7) << 4)));
        }
    };

    f32x4 acc[4][4] = {};
    auto mfma8 = [&](int mq, int nq) {
        __builtin_amdgcn_s_setprio(1);
#pragma unroll
        for (int mi = 0; mi < 2; ++mi)
#pragma unroll
            for (int ni2 = 0; ni2 < 2; ++ni2)
#pragma unroll
                for (int ks = 0; ks < 2; ++ks)
                    acc[mq * 2 + mi][nq * 2 + ni2] = __builtin_amdgcn_mfma_f32_16x16x32_bf16(
                        af[mi][ks], bf[nq * 2 + ni2][ks], acc[mq * 2 + mi][nq * 2 + ni2], 0, 0, 0);
        __builtin_amdgcn_s_setprio(0);
    };

    stageA(0, 0); stageA(0, 1); stageB(0, 0); stageB(0, 1); stageB(1, 0); stageB(1, 1);
    asm volatile("s_waitcnt vmcnt(2)" ::: "memory");
    gbar();

    for (int i = 0; i < 16; ++i) {
        const int u = 2 * i;
        const bool nl = (i < 15);
        loadA2(0, 0); loadB2(0, 0); stageA(u + 1, 0);
        gbar(); lgkm0(); mfma8(0, 0); gbar();
        loadB2(0, 1); stageA(u + 1, 1);
        gbar(); lgkm0(); mfma8(0, 1); gbar();
        loadA2(0, 1); if (nl) stageB(u + 2, 0);
        gbar(); lgkm0(); mfma8(1, 0); gbar();
        if (nl) stageB(u + 2, 1);
        gbar(); mfma8(1, 1);
        if (nl) asm volatile("s_waitcnt vmcnt(2)" ::: "memory");
        else    asm volatile("s_waitcnt vmcnt(0)" ::: "memory");
        gbar();
        loadA2(1, 0); loadB2(1, 0); if (nl) stageA(u + 2, 0);
        gbar(); lgkm0(); mfma8(0, 0); gbar();
        loadB2(1, 1); if (nl) stageA(u + 2, 1);
        gbar(); lgkm0(); mfma8(0, 1); gbar();
        loadA2(1, 1); if (nl) stageB(u + 3, 0);
        gbar(); lgkm0(); mfma8(1, 0); gbar();
        if (nl) stageB(u + 3, 1);
        gbar(); mfma8(1, 1);
        if (nl) asm volatile("s_waitcnt vmcnt(2)" ::: "memory");
        gbar();
    }

#pragma unroll
    for (int mi = 0; mi < 4; ++mi) {
        const int row = m0 + wm * 64 + mi * 16 + l4 * 4;
#pragma unroll
        for (int ni = 0; ni < 4; ++ni) {
            const int col = n0 + wn * 64 + ni * 16 + l15;
#pragma unroll
            for (int r = 0; r < 4; ++r)
                C[(size_t)(row + r) * D_MODEL + col] = acc[mi][ni][r];
        }
    }
}

// ---------------- flash attention v8: KVB=64, tree-reduced softmax ----------------
// 1024 static items, 16 parts/bh sized {11,11,10,10,9,9,8,8,8,10,10,8,8,12,8,4}.
// qi>=3 merged (13 partials/bh, pb_base {0,2,4,7,10} for qi 3..7).
__constant__ unsigned char sl_qi[16] = {7,7,7,6,6,6,5,5,5,4,4,3,3,2,1,0};
__constant__ unsigned char sl_j0[16] = {0,11,22,0,10,19,0,8,16,0,10,0,8,0,0,0};
__constant__ unsigned char sl_j1[16] = {11,22,32,10,19,28,8,16,24,10,20,8,16,12,8,4};
__constant__ unsigned char sl_pt[16] = {0,1,2,0,1,2,0,1,2,0,1,0,1,0,0,0};
__constant__ unsigned char pb_base[5] = {0,2,4,7,10};

__global__ __launch_bounds__(512, 4) void attn6_kernel(const unsigned short* __restrict__ qp,
                                                       const unsigned short* __restrict__ kp,
                                                       const unsigned short* __restrict__ vpT,
                                                       unsigned short* __restrict__ attn_out,
                                                       unsigned short* __restrict__ partO,
                                                       float* __restrict__ ml) {
    __shared__ __align__(16) unsigned short Ks[2][KVB * 64];
    __shared__ __align__(16) unsigned short Vs[2][KVB * 64];

    const int tid = threadIdx.x;
    const int lane = tid & 63;
    const int w = tid >> 6;
    const int l31 = lane & 31, hi = lane >> 5;
    const int sr = tid >> 3, sc = tid & 7;
    const int sgcol = (((sc * 16) ^ ((sr & 7) << 4)) >> 1);
    char* const kdst0 = (char*)Ks[0] + tid * 16;
    char* const kdst1 = (char*)Ks[1] + tid * 16;
    char* const vdst0 = (char*)Vs[0] + tid * 16;
    char* const vdst1 = (char*)Vs[1] + tid * 16;

    const int item = blockIdx.x;
    const int slot = item >> 6;
    const int bh = item & 63;
    const int qi = sl_qi[slot];
    const int j0 = sl_j0[slot];
    const int j1 = sl_j1[slot];
    const int part = sl_pt[slot];
    const bool merged = (qi >= 3);
    const int b = bh >> 5, head = bh & 31, g = head >> 2;
    const int s0 = qi * QBLK;
    const int m = s0 + w * 32 + l31;
    const int mmin = s0 + w * 32;
    const int mmaxw = mmin + 31;

    bf16x8 qf[4];
    {
        const unsigned short* qrow = qp + (size_t)(b * S_LEN + m) * D_MODEL + head * DHEAD + hi * 8;
#pragma unroll
        for (int k = 0; k < 4; ++k)
            qf[k] = *reinterpret_cast<const bf16x8*>(qrow + k * 16);
    }

    const unsigned short* kbase = kp + (size_t)(b * S_LEN + sr) * KV_DIM + g * DHEAD + sgcol;
    const unsigned short* vbase = vpT + (size_t)((b * NG + g) * DHEAD + sr) * S_LEN + sgcol;

    float mrun = -1e30f, lrun = 0.f;
    f32x16 o0 = {}, o1 = {};

    async_copy16(kbase + (size_t)j0 * KVB * KV_DIM, kdst0);
    async_copy16(vbase + j0 * KVB, vdst0);
    asm volatile("s_waitcnt vmcnt(0)" ::: "memory");
    gbar();

    for (int j = j0; j < j1; ++j) {
        const int cur = (j - j0) & 1;
        const int t0 = j * KVB;
        if (j + 1 < j1) {
            async_copy16(kbase + (size_t)(j + 1) * KVB * KV_DIM, cur ? kdst0 : kdst1);
            async_copy16(vbase + (j + 1) * KVB, cur ? vdst0 : vdst1);
        }

        const bool tt0 = (t0 <= mmaxw);
        const bool tt1 = (t0 + 32 <= mmaxw);
        if (tt0) {
            const char* Kb = (const char*)Ks[cur];
            const char* Vb = (const char*)Vs[cur];
            const int rswz0 = (l31 & 7) << 4;

            // ---- S^T = mfma_32x32x16(K, Q) ----
            f32x16 s0v = {}, s1v = {};
#pragma unroll
            for (int k = 0; k < 4; ++k) {
                const int coff = k * 32 + hi * 16;
                const bf16x8 kf0 = *reinterpret_cast<const bf16x8*>(
                    Kb + l31 * 128 + (coff ^ rswz0));
                s0v = __builtin_amdgcn_mfma_f32_32x32x16_bf16(kf0, qf[k], s0v, 0, 0, 0);
                if (tt1) {
                    const bf16x8 kf1 = *reinterpret_cast<const bf16x8*>(
                        Kb + (32 + l31) * 128 + (coff ^ rswz0));
                    s1v = __builtin_amdgcn_mfma_f32_32x32x16_bf16(kf1, qf[k], s1v, 0, 0, 0);
                }
            }

            // ---- in-register online softmax (masks, then tree reductions) ----
            const bool msk = (t0 + KVB - 1) > mmin;
            if (msk) {
#pragma unroll
                for (int r = 0; r < 16; ++r) {
                    const int tloc = (r & 3) + 8 * (r >> 2) + 4 * hi;
                    if (t0 + tloc > m) s0v[r] = -1e30f;
                }
                if (tt1) {
#pragma unroll
                    for (int r = 0; r < 16; ++r) {
                        const int tloc = 32 + (r & 3) + 8 * (r >> 2) + 4 * hi;
                        if (t0 + tloc > m) s1v[r] = -1e30f;
                    }
                }
            }
            float rmax = vmax16(s0v);
            if (tt1) rmax = fmaxf(rmax, vmax16(s1v));
            rmax = fmaxf(rmax, __shfl_xor(rmax, 32, 64));
            if (!__all(rmax <= mrun + 8.0f)) {   // T13 defer-max
                const float mnew = fmaxf(mrun, rmax);
                const float corr = __builtin_amdgcn_exp2f(mrun - mnew);
                lrun *= corr;
#pragma unroll
                for (int r = 0; r < 16; ++r) { o0[r] *= corr; o1[r] *= corr; }
                mrun = mnew;
            }
#pragma unroll
            for (int r = 0; r < 16; ++r)
                s0v[r] = __builtin_amdgcn_exp2f(s0v[r] - mrun);
            if (tt1) {
#pragma unroll
                for (int r = 0; r < 16; ++r)
                    s1v[r] = __builtin_amdgcn_exp2f(s1v[r] - mrun);
            }
            float rs = vsum16(s0v);
            if (tt1) rs += vsum16(s1v);
            rs += __shfl_xor(rs, 32, 64);
            lrun += rs;

            // ---- O^T += mfma_32x32x16(V, P); P built in-register ----
#pragma unroll
            for (int c = 0; c < 4; ++c) {
                if (c >= 2 && !tt1) break;
                const f32x16& sv = (c >> 1) ? s1v : s0v;
                const int h8 = (c & 1) * 8;
                uint32_t a0 = cvtpk(sv[h8 + 0], sv[h8 + 1]);
                uint32_t a1 = cvtpk(sv[h8 + 2], sv[h8 + 3]);
                uint32_t b0 = cvtpk(sv[h8 + 4], sv[h8 + 5]);
                uint32_t b1 = cvtpk(sv[h8 + 6], sv[h8 + 7]);
                plswap(a0, b0); plswap(a1, b1);
                union { uint32_t w4[4]; bf16x8 v; } pf;
                pf.w4[0] = a0; pf.w4[1] = a1; pf.w4[2] = b0; pf.w4[3] = b1;
                const int coff = c * 32 + hi * 16;
                const bf16x8 vf0 = *reinterpret_cast<const bf16x8*>(
                    Vb + l31 * 128 + (coff ^ rswz0));
                o0 = __builtin_amdgcn_mfma_f32_32x32x16_bf16(vf0, pf.v, o0, 0, 0, 0);
                const bf16x8 vf1 = *reinterpret_cast<const bf16x8*>(
                    Vb + (32 + l31) * 128 + (coff ^ rswz0));
                o1 = __builtin_amdgcn_mfma_f32_32x32x16_bf16(vf1, pf.v, o1, 0, 0, 0);
            }
        }
        asm volatile("s_waitcnt vmcnt(0)" ::: "memory");
        gbar();
    }

    if (merged) {
        const int pb = bh * 13 + pb_base[qi - 3] + part;
        const int mrow = w * 32 + l31;
        if (hi == 0) {
            ml[pb * 512 + mrow] = mrun;
            ml[pb * 512 + 256 + mrow] = lrun;
        }
        unsigned short* dst = partO + (size_t)pb * 16384 + mrow * 64 + hi * 4;
#pragma unroll
        for (int qd = 0; qd < 4; ++qd) {
            uint2 pk0, pk1;
            pk0.x = cvtpk(o0[4 * qd + 0], o0[4 * qd + 1]);
            pk0.y = cvtpk(o0[4 * qd + 2], o0[4 * qd + 3]);
            pk1.x = cvtpk(o1[4 * qd + 0], o1[4 * qd + 1]);
            pk1.y = cvtpk(o1[4 * qd + 2], o1[4 * qd + 3]);
            *reinterpret_cast<uint2*>(dst + 8 * qd) = pk0;
            *reinterpret_cast<uint2*>(dst + 32 + 8 * qd) = pk1;
        }
    } else {
        const float inv = 1.0f / lrun;
        unsigned short* dst = attn_out + (size_t)(b * S_LEN + m) * D_MODEL + head * DHEAD + hi * 4;
#pragma unroll
        for (int qd = 0; qd < 4; ++qd) {
            uint2 pk0, pk1;
            pk0.x = cvtpk(o0[4 * qd + 0] * inv, o0[4 * qd + 1] * inv);
            pk0.y = cvtpk(o0[4 * qd + 2] * inv, o0[4 * qd + 3] * inv);
            pk1.x = cvtpk(o1[4 * qd + 0] * inv, o1[4 * qd + 1] * inv);
            pk1.y = cvtpk(o1[4 * qd + 2] * inv, o1[4 * qd + 3] * inv);
            *reinterpret_cast<uint2*>(dst + 8 * qd) = pk0;
            *reinterpret_cast<uint2*>(dst + 32 + 8 * qd) = pk1;
        }
    }
}

// ---------------- merge 2-3 KV-partials (qi 3..7) ----------------
__global__ __launch_bounds__(512) void merge4_kernel(const unsigned short* __restrict__ partO,
                                                     const float* __restrict__ ml,
                                                     unsigned short* __restrict__ attn_out) {
    const int blk = blockIdx.x;          // bh*5 + (qi-3)
    const int bh = blk / 5;
    const int qi = 3 + (blk - bh * 5);
    const int np = (qi >= 5) ? 3 : 2;
    const int pb = bh * 13 + pb_base[qi - 3];
    const int b = bh >> 5, head = bh & 31;
    const int s0 = qi * QBLK;
    const int tid = threadIdx.x;
    const int row = tid >> 1, dh0 = (tid & 1) * 32;

    float m0 = ml[(pb + 0) * 512 + row], l0 = ml[(pb + 0) * 512 + 256 + row];
    float m1 = ml[(pb + 1) * 512 + row], l1 = ml[(pb + 1) * 512 + 256 + row];
    float m2 = -1e30f, l2 = 0.f;
    if (np == 3) { m2 = ml[(pb + 2) * 512 + row]; l2 = ml[(pb + 2) * 512 + 256 + row]; }
    const float M = fmaxf(fmaxf(m0, m1), m2);
    float w0 = __builtin_amdgcn_exp2f(m0 - M);
    float w1 = __builtin_amdgcn_exp2f(m1 - M);
    float w2 = (np == 3) ? __builtin_amdgcn_exp2f(m2 - M) : 0.f;
    const float inv = 1.0f / (l0 * w0 + l1 * w1 + l2 * w2);
    w0 *= inv; w1 *= inv; w2 *= inv;

    const uint4* p0 = reinterpret_cast<const uint4*>(partO + (size_t)(pb + 0) * 16384 + row * 64 + dh0);
    const uint4* p1 = reinterpret_cast<const uint4*>(partO + (size_t)(pb + 1) * 16384 + row * 64 + dh0);
    const uint4* p2 = reinterpret_cast<const uint4*>(partO + (size_t)(pb + 2) * 16384 + row * 64 + dh0);
    unsigned short* dst = attn_out + (size_t)(b * S_LEN + s0 + row) * D_MODEL + head * DHEAD + dh0;
#pragma unroll
    for (int c = 0; c < 4; ++c) {
        union { unsigned short u[8]; uint4 v; } ua, ub, uc, uo;
        ua.v = p0[c]; ub.v = p1[c];
        if (np == 3) uc.v = p2[c];
#pragma unroll
        for (int e = 0; e < 8; e += 2) {
            float x0 = bf2f(ua.u[e]) * w0 + bf2f(ub.u[e]) * w1;
            float x1 = bf2f(ua.u[e + 1]) * w0 + bf2f(ub.u[e + 1]) * w1;
            if (np == 3) {
                x0 += bf2f(uc.u[e]) * w2;
                x1 += bf2f(uc.u[e + 1]) * w2;
            }
            reinterpret_cast<uint32_t*>(uo.u)[e >> 1] = cvtpk(x0, x1);
        }
        reinterpret_cast<uint4*>(dst)[c] = uo.v;
    }
}

// ---------------- host launch ----------------
extern "C" void kernel_launch(void* const* d_in, const int* in_sizes, int n_in,
                              void* d_out, int out_size, void* d_ws, size_t ws_size,
                              hipStream_t stream) {
    const float* q     = (const float*)d_in[0];
    const float* k     = (const float*)d_in[1];
    const float* v     = (const float*)d_in[2];
    const float* w_q   = (const float*)d_in[4];
    const float* w_k   = (const float*)d_in[5];
    const float* w_v   = (const float*)d_in[6];
    const float* w_out = (const float*)d_in[7];

    char* ws = (char*)d_ws;
    size_t off = 0;
    auto alloc = [&](size_t n) { char* p = ws + off; off += (n + 255) & ~(size_t)255; return p; };
    unsigned short* scr1 = (unsigned short*)alloc((size_t)M_TOK * D_MODEL * 2);  // ml scratch
    unsigned short* scr2 = (unsigned short*)alloc((size_t)M_TOK * D_MODEL * 2);  // partO scratch (spans scr2+scr3)
    unsigned short* scr3 = (unsigned short*)alloc((size_t)M_TOK * D_MODEL * 2);
    unsigned short* wqb  = (unsigned short*)alloc((size_t)D_MODEL * D_MODEL * 2);
    unsigned short* wkvb = (unsigned short*)alloc((size_t)2 * KV_DIM * D_MODEL * 2);
    unsigned short* wob  = (unsigned short*)alloc((size_t)D_MODEL * D_MODEL * 2);
    unsigned short* qpb  = (unsigned short*)alloc((size_t)M_TOK * D_MODEL * 2);
    unsigned short* kpb  = (unsigned short*)alloc((size_t)M_TOK * KV_DIM * 2);
    unsigned short* vtb  = (unsigned short*)alloc((size_t)M_TOK * KV_DIM * 2);
    unsigned short* aob  = (unsigned short*)alloc((size_t)M_TOK * D_MODEL * 2);
    (void)scr3;

    // weights-only convert (q/k/v converted inside gemm8p staging)
    cvt_w<<<dim3(5120), dim3(256), 0, stream>>>(w_q, w_k, w_v, w_out, wqb, wkvb, wob);

    // fused q/k/v projections, f32 A inputs
    gemm8p<<<dim3(192), dim3(512), 0, stream>>>(q, k, v, wqb, wkvb, qpb, kpb, vtb);

    // attention: 1024 static balanced items; partO=scr2(+scr3), ml=scr1
    attn6_kernel<<<dim3(1024), dim3(512), 0, stream>>>(qpb, kpb, vtb, aob, scr2, (float*)scr1);
    merge4_kernel<<<dim3(320), dim3(512), 0, stream>>>(scr2, (float*)scr1, aob);

    gemm8o<<<dim3(256), dim3(512), 0, stream>>>(aob, wob, (float*)d_out);
}

// Round 11
// 213.403 us; speedup vs baseline: 1.0468x; 1.0468x over previous
//
#include <hip/hip_runtime.h>
#include <hip/hip_bf16.h>
#include <stdint.h>

#define B_SZ 2
#define S_LEN 2048
#define D_MODEL 2048
#define NH 32
#define NG 8
#define HGRP 4
#define DHEAD 64
#define KV_DIM 512       // NG*DHEAD
#define M_TOK 4096       // B_SZ*S_LEN
#define KVB 64           // attention KV tile
#define QBLK 256

typedef __attribute__((ext_vector_type(8))) short bf16x8;
typedef __attribute__((ext_vector_type(4))) float f32x4;
typedef __attribute__((ext_vector_type(16))) float f32x16;

__device__ inline unsigned short f2bf(float x) {
    uint32_t u = __builtin_bit_cast(uint32_t, x);
    uint32_t r = (u + 0x7fffu + ((u >> 16) & 1u)) >> 16;
    return (unsigned short)r;
}

__device__ inline uint32_t cvtpk(float lo, float hi) {
    uint32_t r;
    asm("v_cvt_pk_bf16_f32 %0, %1, %2" : "=v"(r) : "v"(lo), "v"(hi));
    return r;
}

__device__ inline void plswap(uint32_t& a, uint32_t& b) {
    asm volatile("v_permlane32_swap_b32 %0, %1" : "+v"(a), "+v"(b));
}

__device__ inline float bf2f(unsigned short u) {
    uint32_t x = ((uint32_t)u) << 16;
    return __builtin_bit_cast(float, x);
}

__device__ inline void async_copy16(const void* g, void* l) {
    __builtin_amdgcn_global_load_lds(
        (const __attribute__((address_space(1))) void*)g,
        (__attribute__((address_space(3))) void*)l,
        16, 0, 0);
}

__device__ inline void gbar() {
    asm volatile("" ::: "memory");
    __builtin_amdgcn_s_barrier();
    asm volatile("" ::: "memory");
}
__device__ inline void lgkm0() {
    asm volatile("s_waitcnt lgkmcnt(0)" ::: "memory");
    __builtin_amdgcn_sched_barrier(0);
}

__device__ inline float vmax16(const f32x16& v) {
    float a0 = fmaxf(v[0], v[1]), a1 = fmaxf(v[2], v[3]);
    float a2 = fmaxf(v[4], v[5]), a3 = fmaxf(v[6], v[7]);
    float a4 = fmaxf(v[8], v[9]), a5 = fmaxf(v[10], v[11]);
    float a6 = fmaxf(v[12], v[13]), a7 = fmaxf(v[14], v[15]);
    float b0 = fmaxf(a0, a1), b1 = fmaxf(a2, a3);
    float b2 = fmaxf(a4, a5), b3 = fmaxf(a6, a7);
    return fmaxf(fmaxf(b0, b1), fmaxf(b2, b3));
}
__device__ inline float vsum16(const f32x16& v) {
    float a0 = v[0] + v[1], a1 = v[2] + v[3], a2 = v[4] + v[5], a3 = v[6] + v[7];
    float a4 = v[8] + v[9], a5 = v[10] + v[11], a6 = v[12] + v[13], a7 = v[14] + v[15];
    float b0 = a0 + a1, b1 = a2 + a3, b2 = a4 + a5, b3 = a6 + a7;
    return (b0 + b1) + (b2 + b3);
}

// ---------------- fused f32 -> bf16 convert (all 7 tensors) ----------------
__global__ __launch_bounds__(256) void cvt_all(const float* __restrict__ q,
                                               const float* __restrict__ k,
                                               const float* __restrict__ v,
                                               const float* __restrict__ wq,
                                               const float* __restrict__ wk,
                                               const float* __restrict__ wv,
                                               const float* __restrict__ wo,
                                               unsigned short* __restrict__ qb,
                                               unsigned short* __restrict__ kb,
                                               unsigned short* __restrict__ vb,
                                               unsigned short* __restrict__ wqb,
                                               unsigned short* __restrict__ wkvb,
                                               unsigned short* __restrict__ wob) {
    const int i = blockIdx.x * 256 + threadIdx.x;
    const float* src; unsigned short* dst; int j;
    if (i < 1048576)      { src = q;  dst = qb;  j = i; }
    else if (i < 2097152) { src = k;  dst = kb;  j = i - 1048576; }
    else if (i < 3145728) { src = v;  dst = vb;  j = i - 2097152; }
    else if (i < 3670016) { src = wq; dst = wqb; j = i - 3145728; }
    else if (i < 3801088) { src = wk; dst = wkvb; j = i - 3670016; }
    else if (i < 3932160) { src = wv; dst = wkvb + (size_t)KV_DIM * D_MODEL; j = i - 3801088; }
    else                  { src = wo; dst = wob; j = i - 3932160; }
    const float4* p = reinterpret_cast<const float4*>(src) + (size_t)j * 2;
    float4 a = p[0], b = p[1];
    union { unsigned short u[8]; uint4 v4; } r;
    r.u[0] = f2bf(a.x); r.u[1] = f2bf(a.y); r.u[2] = f2bf(a.z); r.u[3] = f2bf(a.w);
    r.u[4] = f2bf(b.x); r.u[5] = f2bf(b.y); r.u[6] = f2bf(b.z); r.u[7] = f2bf(b.w);
    reinterpret_cast<uint4*>(dst)[j] = r.v4;
}

#define SCALE_Q 0.1803368867f   // 0.125 * log2(e)
#define GK 2048

// ---------------- proj GEMM: 256x128 8-phase, N-stacked q|k|v, 384 blocks ----
// Clone of gemm8o skeleton (96KB LDS, 8 waves 4x2, stageB=1 load, vmcnt(2))
// with 3-mode epilogue (q scaled, k plain, v transposed).
__global__ __launch_bounds__(512, 1) void gemm8p(const unsigned short* __restrict__ Aq,
                                                 const unsigned short* __restrict__ Ak,
                                                 const unsigned short* __restrict__ Av,
                                                 const unsigned short* __restrict__ Bq,
                                                 const unsigned short* __restrict__ Bkv,
                                                 unsigned short* __restrict__ out_q,
                                                 unsigned short* __restrict__ out_k,
                                                 unsigned short* __restrict__ out_v) {
    __shared__ __align__(16) char lds[98304];   // A:[0,64K) dbuf 32K; B:[64K,96K) dbuf 16K

    const int tid = threadIdx.x;
    const int lane = tid & 63;
    const int w = tid >> 6;
    const int wm = w >> 1, wn = w & 1;
    const int l15 = lane & 15, l4 = lane >> 4;

    int bid = blockIdx.x;
    bid = (bid & 7) * 48 + (bid >> 3);      // bijective XCD swizzle, 384 blocks
    const int mb = bid & 15, nb = bid >> 4; // nb 0..23
    const int m0 = mb * 256;

    const unsigned short* A;
    const unsigned short* Bp;
    int mode, n0q;
    if (nb < 16) {
        A = Aq; Bp = Bq + (size_t)(nb * 128) * GK; mode = 0; n0q = nb * 128;
    } else if (nb < 20) {
        A = Ak; Bp = Bkv + (size_t)((nb - 16) * 128) * GK; mode = 1; n0q = (nb - 16) * 128;
    } else {
        A = Av; Bp = Bkv + (size_t)((nb - 20) * 128 + 512) * GK; mode = 2; n0q = (nb - 20) * 128;
    }

    const int srow = tid >> 3;
    const int gcol = (((tid & 7) * 16) ^ ((srow & 7) << 4)) >> 1;

    auto stageA = [&](int tile, int half) {
        char* dst = lds + (tile & 1) * 32768 + half * 16384 + tid * 16;
        const unsigned short* src = A + (size_t)(m0 + half * 128 + srow) * GK + tile * 64 + gcol;
        async_copy16(src, dst);
        async_copy16(src + (size_t)64 * GK, dst + 8192);
    };
    auto stageB = [&](int tile, int half) {
        char* dst = lds + 65536 + (tile & 1) * 16384 + half * 8192 + tid * 16;
        const unsigned short* src = Bp + (size_t)(half * 64 + srow) * GK + tile * 64 + gcol;
        async_copy16(src, dst);
    };

    bf16x8 af[2][2], bf[4][2];
    auto loadA2 = [&](int buf, int mhalf) {
        const char* base = lds + buf * 32768;
#pragma unroll
        for (int mi = 0; mi < 2; ++mi) {
            const int r = wm * 64 + mhalf * 32 + mi * 16 + l15;
#pragma unroll
            for (int ks = 0; ks < 2; ++ks)
                af[mi][ks] = *reinterpret_cast<const bf16x8*>(
                    base + r * 128 + ((ks * 64 + l4 * 16) ^ ((r & 7) << 4)));
        }
    };
    auto loadB2 = [&](int buf, int nhalf) {
        const char* base = lds + 65536 + buf * 16384;
#pragma unroll
        for (int ni2 = 0; ni2 < 2; ++ni2) {
            const int ni = nhalf * 2 + ni2;
            const int r = wn * 64 + ni * 16 + l15;
#pragma unroll
            for (int ks = 0; ks < 2; ++ks)
                bf[ni][ks] = *reinterpret_cast<const bf16x8*>(
                    base + r * 128 + ((ks * 64 + l4 * 16) ^ ((r & 7) << 4)));
        }
    };

    f32x4 acc[4][4] = {};
    auto mfma8 = [&](int mq, int nq) {
        __builtin_amdgcn_s_setprio(1);
#pragma unroll
        for (int mi = 0; mi < 2; ++mi)
#pragma unroll
            for (int ni2 = 0; ni2 < 2; ++ni2)
#pragma unroll
                for (int ks = 0; ks < 2; ++ks)
                    acc[mq * 2 + mi][nq * 2 + ni2] = __builtin_amdgcn_mfma_f32_16x16x32_bf16(
                        af[mi][ks], bf[nq * 2 + ni2][ks], acc[mq * 2 + mi][nq * 2 + ni2], 0, 0, 0);
        __builtin_amdgcn_s_setprio(0);
    };

    stageA(0, 0); stageA(0, 1); stageB(0, 0); stageB(0, 1); stageB(1, 0); stageB(1, 1);
    asm volatile("s_waitcnt vmcnt(2)" ::: "memory");
    gbar();

    for (int i = 0; i < 16; ++i) {
        const int u = 2 * i;
        const bool nl = (i < 15);
        loadA2(0, 0); loadB2(0, 0); stageA(u + 1, 0);
        gbar(); lgkm0(); mfma8(0, 0); gbar();
        loadB2(0, 1); stageA(u + 1, 1);
        gbar(); lgkm0(); mfma8(0, 1); gbar();
        loadA2(0, 1); if (nl) stageB(u + 2, 0);
        gbar(); lgkm0(); mfma8(1, 0); gbar();
        if (nl) stageB(u + 2, 1);
        gbar(); mfma8(1, 1);
        if (nl) asm volatile("s_waitcnt vmcnt(2)" ::: "memory");
        else    asm volatile("s_waitcnt vmcnt(0)" ::: "memory");
        gbar();
        loadA2(1, 0); loadB2(1, 0); if (nl) stageA(u + 2, 0);
        gbar(); lgkm0(); mfma8(0, 0); gbar();
        loadB2(1, 1); if (nl) stageA(u + 2, 1);
        gbar(); lgkm0(); mfma8(0, 1); gbar();
        loadA2(1, 1); if (nl) stageB(u + 3, 0);
        gbar(); lgkm0(); mfma8(1, 0); gbar();
        if (nl) stageB(u + 3, 1);
        gbar(); mfma8(1, 1);
        if (nl) asm volatile("s_waitcnt vmcnt(2)" ::: "memory");
        gbar();
    }

    if (mode == 0) {
#pragma unroll
        for (int mi = 0; mi < 4; ++mi) {
            const int row = m0 + wm * 64 + mi * 16 + l4 * 4;
#pragma unroll
            for (int ni = 0; ni < 4; ++ni) {
                const int col = n0q + wn * 64 + ni * 16 + l15;
#pragma unroll
                for (int r = 0; r < 4; ++r)
                    out_q[(size_t)(row + r) * D_MODEL + col] = f2bf(acc[mi][ni][r] * SCALE_Q);
            }
        }
    } else if (mode == 1) {
#pragma unroll
        for (int mi = 0; mi < 4; ++mi) {
            const int row = m0 + wm * 64 + mi * 16 + l4 * 4;
#pragma unroll
            for (int ni = 0; ni < 4; ++ni) {
                const int col = n0q + wn * 64 + ni * 16 + l15;
#pragma unroll
                for (int r = 0; r < 4; ++r)
                    out_k[(size_t)(row + r) * KV_DIM + col] = f2bf(acc[mi][ni][r]);
            }
        }
    } else {
        const int bb = m0 >> 11;
#pragma unroll
        for (int mi = 0; mi < 4; ++mi) {
            const int tok = (m0 & 2047) + wm * 64 + mi * 16 + l4 * 4;
#pragma unroll
            for (int ni = 0; ni < 4; ++ni) {
                const int c = n0q + wn * 64 + ni * 16 + l15;
                const int g = c >> 6, dh = c & 63;
                uint2 pk;
                pk.x = cvtpk(acc[mi][ni][0], acc[mi][ni][1]);
                pk.y = cvtpk(acc[mi][ni][2], acc[mi][ni][3]);
                *reinterpret_cast<uint2*>(out_v + (size_t)((bb * NG + g) * DHEAD + dh) * S_LEN + tok) = pk;
            }
        }
    }
}

// ---------------- out-proj GEMM: 256x128 8-phase, grid 256 = full GPU ----------------
__global__ __launch_bounds__(512, 1) void gemm8o(const unsigned short* __restrict__ A,
                                                 const unsigned short* __restrict__ B,
                                                 float* __restrict__ C) {
    __shared__ __align__(16) char lds[98304];

    const int tid = threadIdx.x;
    const int lane = tid & 63;
    const int w = tid >> 6;
    const int wm = w >> 1, wn = w & 1;
    const int l15 = lane & 15, l4 = lane >> 4;

    int bid = blockIdx.x;
    bid = (bid & 7) * 32 + (bid >> 3);      // bijective XCD swizzle, 256 blocks
    const int mb = bid & 15, nb = bid >> 4;
    const int m0 = mb * 256, n0 = nb * 128;
    const unsigned short* Bp = B + (size_t)n0 * GK;

    const int srow = tid >> 3;
    const int gcol = (((tid & 7) * 16) ^ ((srow & 7) << 4)) >> 1;

    auto stageA = [&](int tile, int half) {
        char* dst = lds + (tile & 1) * 32768 + half * 16384 + tid * 16;
        const unsigned short* src = A + (size_t)(m0 + half * 128 + srow) * GK + tile * 64 + gcol;
        async_copy16(src, dst);
        async_copy16(src + (size_t)64 * GK, dst + 8192);
    };
    auto stageB = [&](int tile, int half) {
        char* dst = lds + 65536 + (tile & 1) * 16384 + half * 8192 + tid * 16;
        const unsigned short* src = Bp + (size_t)(half * 64 + srow) * GK + tile * 64 + gcol;
        async_copy16(src, dst);
    };

    bf16x8 af[2][2], bf[4][2];
    auto loadA2 = [&](int buf, int mhalf) {
        const char* base = lds + buf * 32768;
#pragma unroll
        for (int mi = 0; mi < 2; ++mi) {
            const int r = wm * 64 + mhalf * 32 + mi * 16 + l15;
#pragma unroll
            for (int ks = 0; ks < 2; ++ks)
                af[mi][ks] = *reinterpret_cast<const bf16x8*>(
                    base + r * 128 + ((ks * 64 + l4 * 16) ^ ((r & 7) << 4)));
        }
    };
    auto loadB2 = [&](int buf, int nhalf) {
        const char* base = lds + 65536 + buf * 16384;
#pragma unroll
        for (int ni2 = 0; ni2 < 2; ++ni2) {
            const int ni = nhalf * 2 + ni2;
            const int r = wn * 64 + ni * 16 + l15;
#pragma unroll
            for (int ks = 0; ks < 2; ++ks)
                bf[ni][ks] = *reinterpret_cast<const bf16x8*>(
                    base + r * 128 + ((ks * 64 + l4 * 16) ^ ((r & 7) << 4)));
        }
    };

    f32x4 acc[4][4] = {};
    auto mfma8 = [&](int mq, int nq) {
        __builtin_amdgcn_s_setprio(1);
#pragma unroll
        for (int mi = 0; mi < 2; ++mi)
#pragma unroll
            for (int ni2 = 0; ni2 < 2; ++ni2)
#pragma unroll
                for (int ks = 0; ks < 2; ++ks)
                    acc[mq * 2 + mi][nq * 2 + ni2] = __builtin_amdgcn_mfma_f32_16x16x32_bf16(
                        af[mi][ks], bf[nq * 2 + ni2][ks], acc[mq * 2 + mi][nq * 2 + ni2], 0, 0, 0);
        __builtin_amdgcn_s_setprio(0);
    };

    stageA(0, 0); stageA(0, 1); stageB(0, 0); stageB(0, 1); stageB(1, 0); stageB(1, 1);
    asm volatile("s_waitcnt vmcnt(2)" ::: "memory");
    gbar();

    for (int i = 0; i < 16; ++i) {
        const int u = 2 * i;
        const bool nl = (i < 15);
        loadA2(0, 0); loadB2(0, 0); stageA(u + 1, 0);
        gbar(); lgkm0(); mfma8(0, 0); gbar();
        loadB2(0, 1); stageA(u + 1, 1);
        gbar(); lgkm0(); mfma8(0, 1); gbar();
        loadA2(0, 1); if (nl) stageB(u + 2, 0);
        gbar(); lgkm0(); mfma8(1, 0); gbar();
        if (nl) stageB(u + 2, 1);
        gbar(); mfma8(1, 1);
        if (nl) asm volatile("s_waitcnt vmcnt(2)" ::: "memory");
        else    asm volatile("s_waitcnt vmcnt(0)" ::: "memory");
        gbar();
        loadA2(1, 0); loadB2(1, 0); if (nl) stageA(u + 2, 0);
        gbar(); lgkm0(); mfma8(0, 0); gbar();
        loadB2(1, 1); if (nl) stageA(u + 2, 1);
        gbar(); lgkm0(); mfma8(0, 1); gbar();
        loadA2(1, 1); if (nl) stageB(u + 3, 0);
        gbar(); lgkm0(); mfma8(1, 0); gbar();
        if (nl) stageB(u + 3, 1);
        gbar(); mfma8(1, 1);
        if (nl) asm volatile("s_waitcnt vmcnt(2)" ::: "memory");
        gbar();
    }

#pragma unroll
    for (int mi = 0; mi < 4; ++mi) {
        const int row = m0 + wm * 64 + mi * 16 + l4 * 4;
#pragma unroll
        for (int ni = 0; ni < 4; ++ni) {
            const int col = n0 + wn * 64 + ni * 16 + l15;
#pragma unroll
            for (int r = 0; r < 4; ++r)
                C[(size_t)(row + r) * D_MODEL + col] = acc[mi][ni][r];
        }
    }
}

// ---------------- flash attention: KVB=64, tree-reduced softmax, static split ----
__constant__ unsigned char sl_qi[16] = {7,7,7,6,6,6,5,5,5,4,4,3,3,2,1,0};
__constant__ unsigned char sl_j0[16] = {0,11,22,0,10,19,0,8,16,0,10,0,8,0,0,0};
__constant__ unsigned char sl_j1[16] = {11,22,32,10,19,28,8,16,24,10,20,8,16,12,8,4};
__constant__ unsigned char sl_pt[16] = {0,1,2,0,1,2,0,1,2,0,1,0,1,0,0,0};
__constant__ unsigned char pb_base[5] = {0,2,4,7,10};

__global__ __launch_bounds__(512, 4) void attn6_kernel(const unsigned short* __restrict__ qp,
                                                       const unsigned short* __restrict__ kp,
                                                       const unsigned short* __restrict__ vpT,
                                                       unsigned short* __restrict__ attn_out,
                                                       unsigned short* __restrict__ partO,
                                                       float* __restrict__ ml) {
    __shared__ __align__(16) unsigned short Ks[2][KVB * 64];
    __shared__ __align__(16) unsigned short Vs[2][KVB * 64];

    const int tid = threadIdx.x;
    const int lane = tid & 63;
    const int w = tid >> 6;
    const int l31 = lane & 31, hi = lane >> 5;
    const int sr = tid >> 3, sc = tid & 7;
    const int sgcol = (((sc * 16) ^ ((sr & 7) << 4)) >> 1);
    char* const kdst0 = (char*)Ks[0] + tid * 16;
    char* const kdst1 = (char*)Ks[1] + tid * 16;
    char* const vdst0 = (char*)Vs[0] + tid * 16;
    char* const vdst1 = (char*)Vs[1] + tid * 16;

    const int item = blockIdx.x;
    const int slot = item >> 6;
    const int bh = item & 63;
    const int qi = sl_qi[slot];
    const int j0 = sl_j0[slot];
    const int j1 = sl_j1[slot];
    const int part = sl_pt[slot];
    const bool merged = (qi >= 3);
    const int b = bh >> 5, head = bh & 31, g = head >> 2;
    const int s0 = qi * QBLK;
    const int m = s0 + w * 32 + l31;
    const int mmin = s0 + w * 32;
    const int mmaxw = mmin + 31;

    bf16x8 qf[4];
    {
        const unsigned short* qrow = qp + (size_t)(b * S_LEN + m) * D_MODEL + head * DHEAD + hi * 8;
#pragma unroll
        for (int k = 0; k < 4; ++k)
            qf[k] = *reinterpret_cast<const bf16x8*>(qrow + k * 16);
    }

    const unsigned short* kbase = kp + (size_t)(b * S_LEN + sr) * KV_DIM + g * DHEAD + sgcol;
    const unsigned short* vbase = vpT + (size_t)((b * NG + g) * DHEAD + sr) * S_LEN + sgcol;

    float mrun = -1e30f, lrun = 0.f;
    f32x16 o0 = {}, o1 = {};

    async_copy16(kbase + (size_t)j0 * KVB * KV_DIM, kdst0);
    async_copy16(vbase + j0 * KVB, vdst0);
    asm volatile("s_waitcnt vmcnt(0)" ::: "memory");
    gbar();

    for (int j = j0; j < j1; ++j) {
        const int cur = (j - j0) & 1;
        const int t0 = j * KVB;
        if (j + 1 < j1) {
            async_copy16(kbase + (size_t)(j + 1) * KVB * KV_DIM, cur ? kdst0 : kdst1);
            async_copy16(vbase + (j + 1) * KVB, cur ? vdst0 : vdst1);
        }

        const bool tt0 = (t0 <= mmaxw);
        const bool tt1 = (t0 + 32 <= mmaxw);
        if (tt0) {
            const char* Kb = (const char*)Ks[cur];
            const char* Vb = (const char*)Vs[cur];
            const int rswz0 = (l31 & 7) << 4;

            // ---- S^T = mfma_32x32x16(K, Q) ----
            f32x16 s0v = {}, s1v = {};
#pragma unroll
            for (int k = 0; k < 4; ++k) {
                const int coff = k * 32 + hi * 16;
                const bf16x8 kf0 = *reinterpret_cast<const bf16x8*>(
                    Kb + l31 * 128 + (coff ^ rswz0));
                s0v = __builtin_amdgcn_mfma_f32_32x32x16_bf16(kf0, qf[k], s0v, 0, 0, 0);
                if (tt1) {
                    const bf16x8 kf1 = *reinterpret_cast<const bf16x8*>(
                        Kb + (32 + l31) * 128 + (coff ^ rswz0));
                    s1v = __builtin_amdgcn_mfma_f32_32x32x16_bf16(kf1, qf[k], s1v, 0, 0, 0);
                }
            }

            // ---- in-register online softmax (masks, then tree reductions) ----
            const bool msk = (t0 + KVB - 1) > mmin;
            if (msk) {
#pragma unroll
                for (int r = 0; r < 16; ++r) {
                    const int tloc = (r & 3) + 8 * (r >> 2) + 4 * hi;
                    if (t0 + tloc > m) s0v[r] = -1e30f;
                }
                if (tt1) {
#pragma unroll
                    for (int r = 0; r < 16; ++r) {
                        const int tloc = 32 + (r & 3) + 8 * (r >> 2) + 4 * hi;
                        if (t0 + tloc > m) s1v[r] = -1e30f;
                    }
                }
            }
            float rmax = vmax16(s0v);
            if (tt1) rmax = fmaxf(rmax, vmax16(s1v));
            rmax = fmaxf(rmax, __shfl_xor(rmax, 32, 64));
            if (!__all(rmax <= mrun + 8.0f)) {   // T13 defer-max
                const float mnew = fmaxf(mrun, rmax);
                const float corr = __builtin_amdgcn_exp2f(mrun - mnew);
                lrun *= corr;
#pragma unroll
                for (int r = 0; r < 16; ++r) { o0[r] *= corr; o1[r] *= corr; }
                mrun = mnew;
            }
#pragma unroll
            for (int r = 0; r < 16; ++r)
                s0v[r] = __builtin_amdgcn_exp2f(s0v[r] - mrun);
            if (tt1) {
#pragma unroll
                for (int r = 0; r < 16; ++r)
                    s1v[r] = __builtin_amdgcn_exp2f(s1v[r] - mrun);
            }
            float rs = vsum16(s0v);
            if (tt1) rs += vsum16(s1v);
            rs += __shfl_xor(rs, 32, 64);
            lrun += rs;

            // ---- O^T += mfma_32x32x16(V, P); P built in-register ----
#pragma unroll
            for (int c = 0; c < 4; ++c) {
                if (c >= 2 && !tt1) break;
                const f32x16& sv = (c >> 1) ? s1v : s0v;
                const int h8 = (c & 1) * 8;
                uint32_t a0 = cvtpk(sv[h8 + 0], sv[h8 + 1]);
                uint32_t a1 = cvtpk(sv[h8 + 2], sv[h8 + 3]);
                uint32_t b0 = cvtpk(sv[h8 + 4], sv[h8 + 5]);
                uint32_t b1 = cvtpk(sv[h8 + 6], sv[h8 + 7]);
                plswap(a0, b0); plswap(a1, b1);
                union { uint32_t w4[4]; bf16x8 v; } pf;
                pf.w4[0] = a0; pf.w4[1] = a1; pf.w4[2] = b0; pf.w4[3] = b1;
                const int coff = c * 32 + hi * 16;
                const bf16x8 vf0 = *reinterpret_cast<const bf16x8*>(
                    Vb + l31 * 128 + (coff ^ rswz0));
                o0 = __builtin_amdgcn_mfma_f32_32x32x16_bf16(vf0, pf.v, o0, 0, 0, 0);
                const bf16x8 vf1 = *reinterpret_cast<const bf16x8*>(
                    Vb + (32 + l31) * 128 + (coff ^ rswz0));
                o1 = __builtin_amdgcn_mfma_f32_32x32x16_bf16(vf1, pf.v, o1, 0, 0, 0);
            }
        }
        asm volatile("s_waitcnt vmcnt(0)" ::: "memory");
        gbar();
    }

    if (merged) {
        const int pb = bh * 13 + pb_base[qi - 3] + part;
        const int mrow = w * 32 + l31;
        if (hi == 0) {
            ml[pb * 512 + mrow] = mrun;
            ml[pb * 512 + 256 + mrow] = lrun;
        }
        unsigned short* dst = partO + (size_t)pb * 16384 + mrow * 64 + hi * 4;
#pragma unroll
        for (int qd = 0; qd < 4; ++qd) {
            uint2 pk0, pk1;
            pk0.x = cvtpk(o0[4 * qd + 0], o0[4 * qd + 1]);
            pk0.y = cvtpk(o0[4 * qd + 2], o0[4 * qd + 3]);
            pk1.x = cvtpk(o1[4 * qd + 0], o1[4 * qd + 1]);
            pk1.y = cvtpk(o1[4 * qd + 2], o1[4 * qd + 3]);
            *reinterpret_cast<uint2*>(dst + 8 * qd) = pk0;
            *reinterpret_cast<uint2*>(dst + 32 + 8 * qd) = pk1;
        }
    } else {
        const float inv = 1.0f / lrun;
        unsigned short* dst = attn_out + (size_t)(b * S_LEN + m) * D_MODEL + head * DHEAD + hi * 4;
#pragma unroll
        for (int qd = 0; qd < 4; ++qd) {
            uint2 pk0, pk1;
            pk0.x = cvtpk(o0[4 * qd + 0] * inv, o0[4 * qd + 1] * inv);
            pk0.y = cvtpk(o0[4 * qd + 2] * inv, o0[4 * qd + 3] * inv);
            pk1.x = cvtpk(o1[4 * qd + 0] * inv, o1[4 * qd + 1] * inv);
            pk1.y = cvtpk(o1[4 * qd + 2] * inv, o1[4 * qd + 3] * inv);
            *reinterpret_cast<uint2*>(dst + 8 * qd) = pk0;
            *reinterpret_cast<uint2*>(dst + 32 + 8 * qd) = pk1;
        }
    }
}

// ---------------- merge 2-3 KV-partials (qi 3..7) ----------------
__global__ __launch_bounds__(512) void merge4_kernel(const unsigned short* __restrict__ partO,
                                                     const float* __restrict__ ml,
                                                     unsigned short* __restrict__ attn_out) {
    const int blk = blockIdx.x;          // bh*5 + (qi-3)
    const int bh = blk / 5;
    const int qi = 3 + (blk - bh * 5);
    const int np = (qi >= 5) ? 3 : 2;
    const int pb = bh * 13 + pb_base[qi - 3];
    const int b = bh >> 5, head = bh & 31;
    const int s0 = qi * QBLK;
    const int tid = threadIdx.x;
    const int row = tid >> 1, dh0 = (tid & 1) * 32;

    float m0 = ml[(pb + 0) * 512 + row], l0 = ml[(pb + 0) * 512 + 256 + row];
    float m1 = ml[(pb + 1) * 512 + row], l1 = ml[(pb + 1) * 512 + 256 + row];
    float m2 = -1e30f, l2 = 0.f;
    if (np == 3) { m2 = ml[(pb + 2) * 512 + row]; l2 = ml[(pb + 2) * 512 + 256 + row]; }
    const float M = fmaxf(fmaxf(m0, m1), m2);
    float w0 = __builtin_amdgcn_exp2f(m0 - M);
    float w1 = __builtin_amdgcn_exp2f(m1 - M);
    float w2 = (np == 3) ? __builtin_amdgcn_exp2f(m2 - M) : 0.f;
    const float inv = 1.0f / (l0 * w0 + l1 * w1 + l2 * w2);
    w0 *= inv; w1 *= inv; w2 *= inv;

    const uint4* p0 = reinterpret_cast<const uint4*>(partO + (size_t)(pb + 0) * 16384 + row * 64 + dh0);
    const uint4* p1 = reinterpret_cast<const uint4*>(partO + (size_t)(pb + 1) * 16384 + row * 64 + dh0);
    const uint4* p2 = reinterpret_cast<const uint4*>(partO + (size_t)(pb + 2) * 16384 + row * 64 + dh0);
    unsigned short* dst = attn_out + (size_t)(b * S_LEN + s0 + row) * D_MODEL + head * DHEAD + dh0;
#pragma unroll
    for (int c = 0; c < 4; ++c) {
        union { unsigned short u[8]; uint4 v; } ua, ub, uc, uo;
        ua.v = p0[c]; ub.v = p1[c];
        if (np == 3) uc.v = p2[c];
#pragma unroll
        for (int e = 0; e < 8; e += 2) {
            float x0 = bf2f(ua.u[e]) * w0 + bf2f(ub.u[e]) * w1;
            float x1 = bf2f(ua.u[e + 1]) * w0 + bf2f(ub.u[e + 1]) * w1;
            if (np == 3) {
                x0 += bf2f(uc.u[e]) * w2;
                x1 += bf2f(uc.u[e + 1]) * w2;
            }
            reinterpret_cast<uint32_t*>(uo.u)[e >> 1] = cvtpk(x0, x1);
        }
        reinterpret_cast<uint4*>(dst)[c] = uo.v;
    }
}

// ---------------- host launch ----------------
extern "C" void kernel_launch(void* const* d_in, const int* in_sizes, int n_in,
                              void* d_out, int out_size, void* d_ws, size_t ws_size,
                              hipStream_t stream) {
    const float* q     = (const float*)d_in[0];
    const float* k     = (const float*)d_in[1];
    const float* v     = (const float*)d_in[2];
    const float* w_q   = (const float*)d_in[4];
    const float* w_k   = (const float*)d_in[5];
    const float* w_v   = (const float*)d_in[6];
    const float* w_out = (const float*)d_in[7];

    char* ws = (char*)d_ws;
    size_t off = 0;
    auto alloc = [&](size_t n) { char* p = ws + off; off += (n + 255) & ~(size_t)255; return p; };
    unsigned short* qb   = (unsigned short*)alloc((size_t)M_TOK * D_MODEL * 2);  // ml after proj
    unsigned short* kb   = (unsigned short*)alloc((size_t)M_TOK * D_MODEL * 2);  // partO after proj
    unsigned short* vb   = (unsigned short*)alloc((size_t)M_TOK * D_MODEL * 2);
    unsigned short* wqb  = (unsigned short*)alloc((size_t)D_MODEL * D_MODEL * 2);
    unsigned short* wkvb = (unsigned short*)alloc((size_t)2 * KV_DIM * D_MODEL * 2);
    unsigned short* wob  = (unsigned short*)alloc((size_t)D_MODEL * D_MODEL * 2);
    unsigned short* qpb  = (unsigned short*)alloc((size_t)M_TOK * D_MODEL * 2);
    unsigned short* kpb  = (unsigned short*)alloc((size_t)M_TOK * KV_DIM * 2);
    unsigned short* vtb  = (unsigned short*)alloc((size_t)M_TOK * KV_DIM * 2);
    unsigned short* aob  = (unsigned short*)alloc((size_t)M_TOK * D_MODEL * 2);

    cvt_all<<<dim3(17408), dim3(256), 0, stream>>>(q, k, v, w_q, w_k, w_v, w_out,
                                                   qb, kb, vb, wqb, wkvb, wob);

    // fused q/k/v projections: 384 blocks of 256x128 (full-GPU fill)
    gemm8p<<<dim3(384), dim3(512), 0, stream>>>(qb, kb, vb, wqb, wkvb, qpb, kpb, vtb);

    // attention: 1024 static balanced items; partO aliases kb(+vb), ml aliases qb
    attn6_kernel<<<dim3(1024), dim3(512), 0, stream>>>(qpb, kpb, vtb, aob, kb, (float*)qb);
    merge4_kernel<<<dim3(320), dim3(512), 0, stream>>>(kb, (float*)qb, aob);

    gemm8o<<<dim3(256), dim3(512), 0, stream>>>(aob, wob, (float*)d_out);
}